// Round 3
// baseline (518.402 us; speedup 1.0000x reference)
//
#include <hip/hip_runtime.h>

// Problem constants (match reference)
#define N_NODES    1000000
#define N_EDGES    16000000
#define D          30
#define WINDOW     5
#define DEG_THRESH 10

// ---- binning params ----
#define P_PARTS    31                 // partitions of 32768 nodes
#define PART_BITS  15
#define PART_SIZE  32768
#define CAP        1081344            // records/bucket: mean 1.0486M + ~32 sigma
#define BUF_CAP    616                // LDS staging entries/bucket (2-iter fill: 528 +3.9sigma)
#define FLUSH_EVERY 2                 // iterations between flushes
#define BIN_BLOCKS 256
#define BIN_THREADS 1024
#define BIN_ITERS  16                 // 256*1024*16 = 4,194,304 groups >= 4M
#define N_GROUPS   (N_EDGES / 4)      // 4,000,000 int4-groups
#define BM_WORDS   (N_NODES / 32)     // 31250 u32 = 125000 B

// dynamic LDS layout for bin_edges
#define L_BM_BYTES   125000
#define L_BUF_BYTES  (P_PARTS * BUF_CAP * 2)   // 38192
#define L_CNT_OFF    (L_BM_BYTES + L_BUF_BYTES)
#define L_TOTAL      (L_CNT_OFF + P_PARTS * 4)   // 163,316 B <= 163,840

// ---- phase 2 ----
#define SLICES     8
#define HIST_WORDS 16384              // 32768 nodes, u32 per 2 nodes (c0:u8|c1:u8)

// ---- ws layout (bytes) ----
#define WS_BM_OFF      0              // u32 bitmask (131072 B reserved)
#define WS_CUR_OFF     131072         // u32[64] bucket cursors
#define WS_PART_OFF    131328         // u32[248 * 16384] slice partials (15.5 MiB)
#define WS_NEEDED      (WS_PART_OFF + (size_t)P_PARTS * SLICES * HIST_WORDS * 4)
#define OUT_BYTES_NEEDED ((size_t)P_PARTS * CAP * 2)   // 67 MB of d_out as scratch

// ---------------------------------------------------------------------------
// Phase 0: pack atom_types into a 1-bit-per-node bitmask; zero bucket cursors.
// ---------------------------------------------------------------------------
__global__ __launch_bounds__(256) void pack_types(
    const int* __restrict__ types,
    unsigned*  __restrict__ bm,
    unsigned*  __restrict__ cursors)
{
    const int g = blockIdx.x * 256 + threadIdx.x;
    const int v = (g < N_NODES) ? types[g] : 0;
    const unsigned long long m = __ballot(v);
    if ((threadIdx.x & 31) == 0 && g < N_NODES)
        bm[g >> 5] = (unsigned)(m >> (threadIdx.x & 32));
    if (blockIdx.x == 0 && threadIdx.x < 64) cursors[threadIdx.x] = 0u;
}

// ---------------------------------------------------------------------------
// Phase 1 v2: single pass over edges -> binned u16 records (local<<1 | ntype).
// Changes vs v1 (which ran 86 us, 19% HBM, barrier-serialized):
//  - flush every 2 iterations (BUF_CAP 616)        -> half the flush overhead
//  - per-wave cursor alloc + shfl broadcast        -> 2 barriers/period, no
//    serialized tid<31 section (17 barriers total vs 49)
//  - software-pipelined edge loads (prefetch next iteration before binning
//    current)                                      -> loads in flight across
//    the flush + barriers
//  - u32 packed flush stores (head/tail scalar fixup for odd base/count)
//    -> half the global store instructions
// ---------------------------------------------------------------------------
__global__ __launch_bounds__(BIN_THREADS, 1) void bin_edges(
    const int*      __restrict__ edge_index,   // [2, N_EDGES] int32
    const unsigned* __restrict__ bm,           // type bitmask (global)
    unsigned short* __restrict__ buckets,      // [P_PARTS][CAP] (in d_out scratch)
    unsigned*       __restrict__ cursors)      // [P_PARTS]
{
    extern __shared__ char smem[];
    unsigned* bm_lds = (unsigned*)smem;                               // 125000 B
    unsigned short (*buf)[BUF_CAP] =
        (unsigned short(*)[BUF_CAP])(smem + L_BM_BYTES);              // 38192 B
    unsigned* cnt = (unsigned*)(smem + L_CNT_OFF);                    // [31]

    const int tid  = threadIdx.x;
    const int w    = tid >> 6, lane = tid & 63;
    for (int i = tid; i < BM_WORDS; i += BIN_THREADS) bm_lds[i] = bm[i];
    if (tid < P_PARTS) cnt[tid] = 0u;
    __syncthreads();

    const int gstart = blockIdx.x * (BIN_ITERS * BIN_THREADS) + tid;

    // prefetch iteration 0
    int4 cs = make_int4(0, 0, 0, 0), cd = make_int4(0, 0, 0, 0);
    if (gstart < N_GROUPS) {
        const int e0 = gstart * 4;
        cs = *reinterpret_cast<const int4*>(edge_index + e0);
        cd = *reinterpret_cast<const int4*>(edge_index + N_EDGES + e0);
    }

    for (int it = 0; it < BIN_ITERS; ++it) {
        const int g  = gstart + it * BIN_THREADS;
        const int gn = g + BIN_THREADS;
        // ---- prefetch next iteration (in flight across bin + flush) ----
        int4 ns = cs, nd = cd;
        const bool nv = (it + 1 < BIN_ITERS) && (gn < N_GROUPS);
        if (nv) {
            const int e0 = gn * 4;
            ns = *reinterpret_cast<const int4*>(edge_index + e0);
            nd = *reinterpret_cast<const int4*>(edge_index + N_EDGES + e0);
        }
        // ---- bin current iteration ----
        if (g < N_GROUPS) {
            const int ss[4] = {cs.x, cs.y, cs.z, cs.w};
            const int dd[4] = {cd.x, cd.y, cd.z, cd.w};
#pragma unroll
            for (int k = 0; k < 4; ++k) {
                const int s = ss[k], d = dd[k];
                const unsigned ts = (bm_lds[(unsigned)s >> 5] >> (s & 31)) & 1u;
                const unsigned td = (bm_lds[(unsigned)d >> 5] >> (d & 31)) & 1u;
                {   // record for endpoint s carries d's type
                    const int b = s >> PART_BITS;
                    const unsigned short rec =
                        (unsigned short)(((s & (PART_SIZE - 1)) << 1) | td);
                    const unsigned pos = atomicAdd(&cnt[b], 1u);
                    if (pos < BUF_CAP) buf[b][pos] = rec;
                    else {  // statistically ~never: direct spill
                        const unsigned gp = atomicAdd(&cursors[b], 1u);
                        if (gp < CAP) buckets[(size_t)b * CAP + gp] = rec;
                    }
                }
                {   // record for endpoint d carries s's type
                    const int b = d >> PART_BITS;
                    const unsigned short rec =
                        (unsigned short)(((d & (PART_SIZE - 1)) << 1) | ts);
                    const unsigned pos = atomicAdd(&cnt[b], 1u);
                    if (pos < BUF_CAP) buf[b][pos] = rec;
                    else {
                        const unsigned gp = atomicAdd(&cursors[b], 1u);
                        if (gp < CAP) buckets[(size_t)b * CAP + gp] = rec;
                    }
                }
            }
        }
        cs = ns; cd = nd;

        // ---- flush every FLUSH_EVERY iterations ----
        if ((it & (FLUSH_EVERY - 1)) == (FLUSH_EVERY - 1)) {
            __syncthreads();   // all records staged
            // per-wave alloc: lane 0/1 own buckets 2w, 2w+1
            unsigned myc = 0u, mybase = 0u;
            const int ab = w * 2 + lane;
            if (lane < 2 && ab < P_PARTS) {
                unsigned c = cnt[ab]; if (c > BUF_CAP) c = BUF_CAP;
                unsigned bse = 0u;
                if (c) {
                    bse = atomicAdd(&cursors[ab], c);
                    if (bse > CAP) bse = CAP;
                    if (bse + c > CAP) c = CAP - bse;   // memory-safety clamp
                }
                cnt[ab] = 0u;
                myc = c; mybase = bse;
            }
            const unsigned c0 = __shfl(myc, 0), base0 = __shfl(mybase, 0);
            const unsigned c1 = __shfl(myc, 1), base1 = __shfl(mybase, 1);
#pragma unroll
            for (int j = 0; j < 2; ++j) {
                const int b = w * 2 + j;
                const unsigned c    = j ? c1 : c0;
                const unsigned base = j ? base1 : base0;
                if (b < P_PARTS && c > 0u) {
                    unsigned short* dst = buckets + (size_t)b * CAP;
                    const unsigned head = base & 1u;
                    if (head && lane == 0) dst[base] = buf[b][0];
                    const unsigned body = c - head;
                    const unsigned n2   = body >> 1;
                    unsigned* dst32 = reinterpret_cast<unsigned*>(dst + base + head);
                    if (head == 0u) {   // normal case: aligned LDS + global u32
                        const unsigned* src32 =
                            reinterpret_cast<const unsigned*>(&buf[b][0]);
                        for (unsigned e = lane; e < n2; e += 64)
                            dst32[e] = src32[e];
                    } else {            // post-spill odd base: ultra-rare
                        for (unsigned e = lane; e < n2; e += 64) {
                            const unsigned lo = buf[b][1 + 2 * e];
                            const unsigned hi = buf[b][2 + 2 * e];
                            dst32[e] = lo | (hi << 16);
                        }
                    }
                    if ((body & 1u) && lane == 0) dst[base + c - 1] = buf[b][c - 1];
                }
            }
            __syncthreads();   // buffers reusable
        }
    }
}

// ---------------------------------------------------------------------------
// Phase 2: per (partition, slice) block builds a 64 KB LDS histogram
// (c0:u8 | c1:u8 per node, 2 nodes per u32) from its record slice.
// ---------------------------------------------------------------------------
__global__ __launch_bounds__(512) void hist_pass(
    const unsigned short* __restrict__ buckets,
    const unsigned*       __restrict__ cursors,
    unsigned*             __restrict__ partials)   // [P*SLICES][HIST_WORDS]
{
    __shared__ unsigned hist[HIST_WORDS];          // exactly 64 KiB
    const int p = blockIdx.x >> 3, s = blockIdx.x & 7;
    const int tid = threadIdx.x;
    for (int i = tid; i < HIST_WORDS; i += 512) hist[i] = 0u;
    __syncthreads();

    unsigned count = cursors[p]; if (count > CAP) count = CAP;
    const unsigned short* bk = buckets + (size_t)p * CAP;
    const unsigned n4 = (count + 3u) >> 2;
    for (unsigned j = (unsigned)(s * 512 + tid); j < n4; j += SLICES * 512) {
        const unsigned i0 = j * 4u;
        if (i0 + 4u <= count) {
            const ushort4 r4 = *reinterpret_cast<const ushort4*>(bk + i0);
            const unsigned short rr[4] = {r4.x, r4.y, r4.z, r4.w};
#pragma unroll
            for (int k = 0; k < 4; ++k) {
                const unsigned rec = rr[k];
                const unsigned local = rec >> 1, t = rec & 1u;
                atomicAdd(&hist[local >> 1], (1u << (8u * t)) << (16u * (local & 1u)));
            }
        } else {
            for (unsigned i = i0; i < count; ++i) {
                const unsigned rec = bk[i];
                const unsigned local = rec >> 1, t = rec & 1u;
                atomicAdd(&hist[local >> 1], (1u << (8u * t)) << (16u * (local & 1u)));
            }
        }
    }
    __syncthreads();
    unsigned* op = partials + (size_t)blockIdx.x * HIST_WORDS;
    for (int i = tid; i < HIST_WORDS; i += 512) op[i] = hist[i];
}

// ---------------------------------------------------------------------------
// Phase 3 (fused reduce + output) v3: per-wave coalesced staging.
// Each wave owns 64 contiguous rows (= 960 float2): stage-in with 15 fully-
// coalesced dwordx2 loads/lane -> padded LDS tile (ROW_PAD=33 -> row reads are
// 2-way = free); compute (register row, 5 dots vs W^T in LDS); assemble the
// output row in the same LDS tile and store with 15 coalesced dwordx2/lane.
// ---------------------------------------------------------------------------
#define WT_STRIDE  36
#define OT_THREADS 256
#define OT_ROWPAD  33
__global__ __launch_bounds__(OT_THREADS) void out_pass(
    const float* __restrict__ x, const float* __restrict__ Wm,
    const unsigned* __restrict__ partials,
    const unsigned* __restrict__ bm,
    float* __restrict__ out)
{
    __shared__ float sWt[D * WT_STRIDE];                    // 4320 B
    __shared__ float stg[OT_THREADS / 64][64 * OT_ROWPAD];  // 4 x 8448 B
    const int tid = threadIdx.x;
    for (int i = tid; i < D * D; i += OT_THREADS) {
        const int k = i / D, c = i - k * D;   // Wm is [k][c] row-major
        sWt[c * WT_STRIDE + k] = Wm[i];
    }

    const int wv = tid >> 6, lane = tid & 63;
    const long blockBase = (long)blockIdx.x * OT_THREADS;   // first node of block
    const long waveBase  = blockBase + (long)wv * 64;       // first node of wave
    float* ws = stg[wv];
    const long f2base = waveBase * 15;                      // wave's first float2
    const long f2lim  = (long)N_NODES * 15;                 // total float2 in x/out

    // ---- stage-in: 960 contiguous float2, fully coalesced ----
    const float2* gx = reinterpret_cast<const float2*>(x);
#pragma unroll
    for (int it = 0; it < 15; ++it) {
        const int g = it * 64 + lane;               // 0..959
        const int row = g / 15, c2 = g - row * 15;
        float2 v = make_float2(0.0f, 0.0f);
        if (f2base + g < f2lim) v = gx[f2base + g];
        ws[row * OT_ROWPAD + 2 * c2]     = v.x;
        ws[row * OT_ROWPAD + 2 * c2 + 1] = v.y;
    }
    __syncthreads();   // covers sWt + cross-lane stage-in

    // ---- criterion (window start) for this node ----
    const long n = blockBase + tid;
    int start = 0;
    if (n < N_NODES) {
        const unsigned Wd   = (unsigned)(n >> 1);   // partials word = 2 nodes
        const unsigned h    = (unsigned)n & 1u;
        const unsigned p    = Wd >> 14;
        const unsigned widx = Wd & 16383u;
        const unsigned* pp  = partials + (size_t)(p * SLICES) * HIST_WORDS + widx;
        unsigned sum = 0u;
#pragma unroll
        for (int s = 0; s < SLICES; ++s) sum += pp[(size_t)s * HIST_WORDS];
        const unsigned c0 = (sum >> (16u * h)) & 0xFFu;
        const unsigned c1 = (sum >> (16u * h + 8u)) & 0xFFu;
        const unsigned t  = (bm[n >> 5] >> ((unsigned)n & 31u)) & 1u;
        const unsigned cnt    = c0 + c1;
        const unsigned same_c = t ? c1 : c0;
        const unsigned diff_c = t ? c0 : c1;
        const int mix  = diff_c ? 0 : (same_c ? (int)t + 1 : 0);
        const int crit = (cnt > DEG_THRESH ? 3 : 0) + mix;
        start = crit * WINDOW;
    }

    // ---- own row -> registers (bank = (lane+k)%32 -> 2-way = free) ----
    float xr[D];
#pragma unroll
    for (int k = 0; k < D; ++k) xr[k] = ws[lane * OT_ROWPAD + k];

    // ---- 5 dots against W^T columns ----
    float acc[WINDOW];
    const float* wc0 = &sWt[start * WT_STRIDE];
#pragma unroll
    for (int j = 0; j < WINDOW; ++j) {
        const float* wc = wc0 + j * WT_STRIDE;
        float a = 0.0f;
#pragma unroll
        for (int k = 0; k < D; ++k) a += xr[k] * wc[k];
        acc[j] = a * 0.18257418583505536f;   // 1/sqrt(30)
    }
    __syncthreads();   // all row reads done before rows are overwritten

    // ---- assemble output row in LDS (own row only) ----
    float* wr = ws + lane * OT_ROWPAD;
#pragma unroll
    for (int k = 0; k < D; ++k) wr[k] = 0.0f;
#pragma unroll
    for (int j = 0; j < WINDOW; ++j) wr[start + j] = acc[j];
    __syncthreads();   // cross-lane before coalesced store

    // ---- stage-out: 960 contiguous float2, fully coalesced ----
    float2* gout = reinterpret_cast<float2*>(out);
#pragma unroll
    for (int it = 0; it < 15; ++it) {
        const int g = it * 64 + lane;
        const int row = g / 15, c2 = g - row * 15;
        if (f2base + g < f2lim)
            gout[f2base + g] = make_float2(ws[row * OT_ROWPAD + 2 * c2],
                                           ws[row * OT_ROWPAD + 2 * c2 + 1]);
    }
}

// ===========================================================================
// Fallback (round-2 atomic path) if buffers are unexpectedly small.
// ===========================================================================
#define SAME_INC (1u << 12)
#define DIFF_INC (1u << 22)

__global__ __launch_bounds__(256) void edge_pass_atomic(
    const int* __restrict__ edge_index, const int* __restrict__ atom_types,
    unsigned* __restrict__ agg)
{
    const int t  = blockIdx.x * blockDim.x + threadIdx.x;
    const int e0 = t * 4;
    if (e0 >= N_EDGES) return;
    const int4 s4 = *reinterpret_cast<const int4*>(edge_index + e0);
    const int4 d4 = *reinterpret_cast<const int4*>(edge_index + N_EDGES + e0);
    const int ss[4] = {s4.x, s4.y, s4.z, s4.w};
    const int dd[4] = {d4.x, d4.y, d4.z, d4.w};
#pragma unroll
    for (int k = 0; k < 4; ++k) {
        const int s = ss[k], d = dd[k];
        const unsigned add = 1u + ((atom_types[s] == atom_types[d]) ? SAME_INC : DIFF_INC);
        atomicAdd(agg + s, add);
        atomicAdd(agg + d, add);
    }
}

__global__ __launch_bounds__(256) void out_pass_agg(
    const float* __restrict__ x, const float* __restrict__ Wm,
    const unsigned* __restrict__ agg, const int* __restrict__ atom_types,
    float* __restrict__ out)
{
    __shared__ float sx[64 * D];
    __shared__ float sW[D * D];
    __shared__ int   sstart[64];
    const int tid   = threadIdx.x;
    const long base = (long)blockIdx.x * 64;
    for (int i = tid; i < D * D; i += 256) sW[i] = Wm[i];
    const float* xb = x + base * D;
    for (int i = tid; i < 64 * D; i += 256) sx[i] = xb[i];
    if (tid < 64) {
        const long n = base + tid;
        const unsigned a = agg[n];
        const int cnt = a & 0xFFFu, sc = (a >> 12) & 0x3FFu, dc = a >> 22;
        const int mix  = dc ? 0 : (sc ? atom_types[n] + 1 : 0);
        sstart[tid] = ((cnt > DEG_THRESH ? 3 : 0) + mix) * WINDOW;
    }
    __syncthreads();
    const float scale = 0.18257418583505536f;
    float* ob = out + base * D;
    for (int i = tid; i < 64 * D; i += 256) {
        const int nd = i / D, c = i - nd * D;
        float v = 0.0f;
        if ((unsigned)(c - sstart[nd]) < WINDOW) {
            float acc = 0.0f;
#pragma unroll
            for (int k = 0; k < D; ++k) acc += sx[nd * D + k] * sW[k * D + c];
            v = acc * scale;
        }
        ob[i] = v;
    }
}

// ---------------------------------------------------------------------------
extern "C" void kernel_launch(void* const* d_in, const int* in_sizes, int n_in,
                              void* d_out, int out_size, void* d_ws, size_t ws_size,
                              hipStream_t stream)
{
    const float* x          = (const float*)d_in[0];
    const float* Wm         = (const float*)d_in[1];
    const int*   edge_index = (const int*)d_in[2];
    const int*   atom_types = (const int*)d_in[3];
    float* out = (float*)d_out;

    if (ws_size >= WS_NEEDED && (size_t)out_size * 4 >= OUT_BYTES_NEEDED) {
        char* ws = (char*)d_ws;
        unsigned*       bm       = (unsigned*)(ws + WS_BM_OFF);
        unsigned*       cursors  = (unsigned*)(ws + WS_CUR_OFF);
        unsigned*       partials = (unsigned*)(ws + WS_PART_OFF);
        unsigned short* buckets  = (unsigned short*)d_out;   // scratch, overwritten

        pack_types<<<(N_NODES + 255) / 256, 256, 0, stream>>>(atom_types, bm, cursors);
        bin_edges<<<BIN_BLOCKS, BIN_THREADS, L_TOTAL, stream>>>(edge_index, bm,
                                                                buckets, cursors);
        hist_pass<<<P_PARTS * SLICES, 512, 0, stream>>>(buckets, cursors, partials);
        out_pass<<<(N_NODES + OT_THREADS - 1) / OT_THREADS, OT_THREADS, 0, stream>>>(
            x, Wm, partials, bm, out);
    } else {
        unsigned* agg = (unsigned*)d_ws;
        hipMemsetAsync(agg, 0x00, N_NODES * sizeof(unsigned), stream);
        edge_pass_atomic<<<(N_EDGES / 4) / 256, 256, 0, stream>>>(edge_index, atom_types, agg);
        out_pass_agg<<<N_NODES / 64, 256, 0, stream>>>(x, Wm, agg, atom_types, out);
    }
}

// Round 4
// 374.686 us; speedup vs baseline: 1.3836x; 1.3836x over previous
//
#include <hip/hip_runtime.h>

// Problem constants (match reference)
#define N_NODES    1000000
#define N_EDGES    16000000
#define D          30
#define WINDOW     5
#define DEG_THRESH 10

// ---- binning params ----
#define P_PARTS    31                 // partitions of 32768 nodes
#define PART_BITS  15
#define PART_SIZE  32768
#define CAP        1081344            // records/bucket: mean 1.0486M + ~32 sigma
#define BUF_CAP    512                // LDS staging entries per bucket
#define BIN_BLOCKS 256
#define BIN_THREADS 1024
#define BIN_ITERS  16                 // 256*1024*16 = 4,194,304 groups >= 4M
#define N_GROUPS   (N_EDGES / 4)      // 4,000,000 int4-groups
#define BM_WORDS   (N_NODES / 32)     // 31250 u32 = 125000 B

// dynamic LDS layout for bin_edges
#define L_BM_BYTES   125000
#define L_BUF_BYTES  (P_PARTS * BUF_CAP * 2)   // 31744
#define L_CNT_OFF    (L_BM_BYTES + L_BUF_BYTES)
#define L_TOTAL      (L_CNT_OFF + P_PARTS * 4 * 3)   // 157,488 B <= 160 KiB

// ---- phase 2 ----
#define SLICES     8
#define HIST_WORDS 16384              // 32768 nodes, u32 per 2 nodes (c0:u8|c1:u8)

// ---- ws layout (bytes) ----
#define WS_BM_OFF      0              // u32 bitmask (131072 B reserved)
#define WS_CUR_OFF     131072         // u32[64] bucket cursors
#define WS_PART_OFF    131328         // u32[248 * 16384] slice partials (15.5 MiB)
#define WS_NEEDED      (WS_PART_OFF + (size_t)P_PARTS * SLICES * HIST_WORDS * 4)
#define OUT_BYTES_NEEDED ((size_t)P_PARTS * CAP * 2)   // 67 MB of d_out as scratch

// ---------------------------------------------------------------------------
// Phase 0: pack atom_types into a 1-bit-per-node bitmask; zero bucket cursors.
// ---------------------------------------------------------------------------
__global__ __launch_bounds__(256) void pack_types(
    const int* __restrict__ types,
    unsigned*  __restrict__ bm,
    unsigned*  __restrict__ cursors)
{
    const int g = blockIdx.x * 256 + threadIdx.x;
    const int v = (g < N_NODES) ? types[g] : 0;
    const unsigned long long m = __ballot(v);
    if ((threadIdx.x & 31) == 0 && g < N_NODES)
        bm[g >> 5] = (unsigned)(m >> (threadIdx.x & 32));
    if (blockIdx.x == 0 && threadIdx.x < 64) cursors[threadIdx.x] = 0u;
}

// ---------------------------------------------------------------------------
// Phase 1 (EXACT round-2 revert): single pass over edges -> binned u16
// records (local_id<<1 | ntype). Round-3's hand-pipelined variant regressed
// 86->217 us: the explicit prefetch pushed the compiler into a 32-VGPR
// minimal-live-range schedule that sank the edge loads to their uses and
// exposed ~900cy HBM latency (VALUBusy 24->9%). Do NOT hand-pipeline this
// kernel; the 44-VGPR compiler schedule already hides the latency.
// ---------------------------------------------------------------------------
__global__ __launch_bounds__(BIN_THREADS, 1) void bin_edges(
    const int*      __restrict__ edge_index,   // [2, N_EDGES] int32
    const unsigned* __restrict__ bm,           // type bitmask (global)
    unsigned short* __restrict__ buckets,      // [P_PARTS][CAP] (in d_out scratch)
    unsigned*       __restrict__ cursors)      // [P_PARTS]
{
    extern __shared__ char smem[];
    unsigned* bm_lds = (unsigned*)smem;                               // 125000 B
    unsigned short (*buf)[BUF_CAP] =
        (unsigned short(*)[BUF_CAP])(smem + L_BM_BYTES);              // 31744 B
    unsigned* cnt   = (unsigned*)(smem + L_CNT_OFF);                  // [31]
    unsigned* basev = cnt + P_PARTS;
    unsigned* ccnt  = basev + P_PARTS;

    const int tid = threadIdx.x;
    for (int i = tid; i < BM_WORDS; i += BIN_THREADS) bm_lds[i] = bm[i];
    if (tid < P_PARTS) cnt[tid] = 0u;
    __syncthreads();

    for (int it = 0; it < BIN_ITERS; ++it) {
        const int g = (blockIdx.x * BIN_ITERS + it) * BIN_THREADS + tid;
        if (g < N_GROUPS) {
            const int e0 = g * 4;
            const int4 s4 = *reinterpret_cast<const int4*>(edge_index + e0);
            const int4 d4 = *reinterpret_cast<const int4*>(edge_index + N_EDGES + e0);
            const int ss[4] = {s4.x, s4.y, s4.z, s4.w};
            const int dd[4] = {d4.x, d4.y, d4.z, d4.w};
#pragma unroll
            for (int k = 0; k < 4; ++k) {
                const int s = ss[k], d = dd[k];
                const unsigned ts = (bm_lds[(unsigned)s >> 5] >> (s & 31)) & 1u;
                const unsigned td = (bm_lds[(unsigned)d >> 5] >> (d & 31)) & 1u;
                {   // record for endpoint s carries d's type
                    const int b = s >> PART_BITS;
                    const unsigned short rec =
                        (unsigned short)(((s & (PART_SIZE - 1)) << 1) | td);
                    const unsigned pos = atomicAdd(&cnt[b], 1u);
                    if (pos < BUF_CAP) buf[b][pos] = rec;
                    else {  // statistically ~never: direct spill
                        const unsigned gp = atomicAdd(&cursors[b], 1u);
                        if (gp < CAP) buckets[(size_t)b * CAP + gp] = rec;
                    }
                }
                {   // record for endpoint d carries s's type
                    const int b = d >> PART_BITS;
                    const unsigned short rec =
                        (unsigned short)(((d & (PART_SIZE - 1)) << 1) | ts);
                    const unsigned pos = atomicAdd(&cnt[b], 1u);
                    if (pos < BUF_CAP) buf[b][pos] = rec;
                    else {
                        const unsigned gp = atomicAdd(&cursors[b], 1u);
                        if (gp < CAP) buckets[(size_t)b * CAP + gp] = rec;
                    }
                }
            }
        }
        __syncthreads();
        if (tid < P_PARTS) {
            unsigned c = cnt[tid]; if (c > BUF_CAP) c = BUF_CAP;
            unsigned bse = 0u;
            if (c) {
                bse = atomicAdd(&cursors[tid], c);
                if (bse > CAP) bse = CAP;
                if (bse + c > CAP) c = CAP - bse;   // memory-safety clamp
            }
            ccnt[tid] = c; basev[tid] = bse; cnt[tid] = 0u;
        }
        __syncthreads();
        // coalesced flush: wave w copies buckets 2w, 2w+1
        const int w = tid >> 6, lane = tid & 63;
#pragma unroll
        for (int j = 0; j < 2; ++j) {
            const int b = w * 2 + j;
            if (b < P_PARTS) {
                const unsigned c = ccnt[b];
                unsigned short* dst = buckets + (size_t)b * CAP + basev[b];
                for (unsigned e = lane; e < c; e += 64) dst[e] = buf[b][e];
            }
        }
        __syncthreads();
    }
}

// ---------------------------------------------------------------------------
// Phase 2: per (partition, slice) block builds a 64 KB LDS histogram
// (c0:u8 | c1:u8 per node, 2 nodes per u32) from its record slice.
// ---------------------------------------------------------------------------
__global__ __launch_bounds__(512) void hist_pass(
    const unsigned short* __restrict__ buckets,
    const unsigned*       __restrict__ cursors,
    unsigned*             __restrict__ partials)   // [P*SLICES][HIST_WORDS]
{
    __shared__ unsigned hist[HIST_WORDS];          // exactly 64 KiB
    const int p = blockIdx.x >> 3, s = blockIdx.x & 7;
    const int tid = threadIdx.x;
    for (int i = tid; i < HIST_WORDS; i += 512) hist[i] = 0u;
    __syncthreads();

    unsigned count = cursors[p]; if (count > CAP) count = CAP;
    const unsigned short* bk = buckets + (size_t)p * CAP;
    const unsigned n4 = (count + 3u) >> 2;
    for (unsigned j = (unsigned)(s * 512 + tid); j < n4; j += SLICES * 512) {
        const unsigned i0 = j * 4u;
        if (i0 + 4u <= count) {
            const ushort4 r4 = *reinterpret_cast<const ushort4*>(bk + i0);
            const unsigned short rr[4] = {r4.x, r4.y, r4.z, r4.w};
#pragma unroll
            for (int k = 0; k < 4; ++k) {
                const unsigned rec = rr[k];
                const unsigned local = rec >> 1, t = rec & 1u;
                atomicAdd(&hist[local >> 1], (1u << (8u * t)) << (16u * (local & 1u)));
            }
        } else {
            for (unsigned i = i0; i < count; ++i) {
                const unsigned rec = bk[i];
                const unsigned local = rec >> 1, t = rec & 1u;
                atomicAdd(&hist[local >> 1], (1u << (8u * t)) << (16u * (local & 1u)));
            }
        }
    }
    __syncthreads();
    unsigned* op = partials + (size_t)blockIdx.x * HIST_WORDS;
    for (int i = tid; i < HIST_WORDS; i += 512) op[i] = hist[i];
}

// ---------------------------------------------------------------------------
// Phase 3 (fused reduce + output) v4: per-wave coalesced staging with
// float4 global transfers. Each wave owns 64 contiguous rows = 480 float4.
// Stage-in: 8 dwordx4 loads/lane (1 KB/wave-instr) element-scattered into the
// padded LDS tile (ROW_PAD=33; 15 float4 span exactly 2 rows; a float4 never
// spans >2 rows). Compute: register row (2-way bank = free), 5 dots vs W^T.
// Stage-out: gather 4 floats from LDS, 8 dwordx4 stores/lane. Half the
// global memory instructions of the float2 version, same LDS op count.
// ---------------------------------------------------------------------------
#define WT_STRIDE  36
#define OT_THREADS 256
#define OT_ROWPAD  33
__global__ __launch_bounds__(OT_THREADS) void out_pass(
    const float* __restrict__ x, const float* __restrict__ Wm,
    const unsigned* __restrict__ partials,
    const unsigned* __restrict__ bm,
    float* __restrict__ out)
{
    __shared__ float sWt[D * WT_STRIDE];                    // 4320 B
    __shared__ float stg[OT_THREADS / 64][64 * OT_ROWPAD];  // 4 x 8448 B
    const int tid = threadIdx.x;
    for (int i = tid; i < D * D; i += OT_THREADS) {
        const int k = i / D, c = i - k * D;   // Wm is [k][c] row-major
        sWt[c * WT_STRIDE + k] = Wm[i];
    }

    const int wv = tid >> 6, lane = tid & 63;
    const long blockBase = (long)blockIdx.x * OT_THREADS;   // first node of block
    const long waveBase  = blockBase + (long)wv * 64;       // first node of wave
    float* ws = stg[wv];
    const long f4base = (waveBase >> 1) * 15;               // wave's first float4
    const long f4lim  = (long)N_NODES * (D / 2) / 2;        // 7,500,000 float4 total

    // ---- stage-in: 480 contiguous float4, fully coalesced ----
    const float4* gx = reinterpret_cast<const float4*>(x);
#pragma unroll
    for (int it = 0; it < 8; ++it) {
        const int g = it * 64 + lane;               // 0..511, active < 480
        if (g < 480) {
            float4 v = make_float4(0.0f, 0.0f, 0.0f, 0.0f);
            if (f4base + g < f4lim) v = gx[f4base + g];
            const int pair = g / 15, within = g - pair * 15;
            const int r0 = pair * 2, f0 = within * 4;       // f0 in [0,56]
            const float vv[4] = {v.x, v.y, v.z, v.w};
#pragma unroll
            for (int e = 0; e < 4; ++e) {
                const int ff = f0 + e;                      // float idx in 2-row pair
                const int r  = r0 + (ff >= D);
                const int c  = ff - ((ff >= D) ? D : 0);
                ws[r * OT_ROWPAD + c] = vv[e];
            }
        }
    }
    __syncthreads();   // covers sWt + cross-lane stage-in

    // ---- criterion (window start) for this node ----
    const long n = blockBase + tid;
    int start = 0;
    if (n < N_NODES) {
        const unsigned Wd   = (unsigned)(n >> 1);   // partials word = 2 nodes
        const unsigned h    = (unsigned)n & 1u;
        const unsigned p    = Wd >> 14;
        const unsigned widx = Wd & 16383u;
        const unsigned* pp  = partials + (size_t)(p * SLICES) * HIST_WORDS + widx;
        unsigned sum = 0u;
#pragma unroll
        for (int s = 0; s < SLICES; ++s) sum += pp[(size_t)s * HIST_WORDS];
        const unsigned c0 = (sum >> (16u * h)) & 0xFFu;
        const unsigned c1 = (sum >> (16u * h + 8u)) & 0xFFu;
        const unsigned t  = (bm[n >> 5] >> ((unsigned)n & 31u)) & 1u;
        const unsigned cnt    = c0 + c1;
        const unsigned same_c = t ? c1 : c0;
        const unsigned diff_c = t ? c0 : c1;
        const int mix  = diff_c ? 0 : (same_c ? (int)t + 1 : 0);
        const int crit = (cnt > DEG_THRESH ? 3 : 0) + mix;
        start = crit * WINDOW;
    }

    // ---- own row -> registers (bank = (lane+k)%32 -> 2-way = free) ----
    float xr[D];
#pragma unroll
    for (int k = 0; k < D; ++k) xr[k] = ws[lane * OT_ROWPAD + k];

    // ---- 5 dots against W^T columns ----
    float acc[WINDOW];
    const float* wc0 = &sWt[start * WT_STRIDE];
#pragma unroll
    for (int j = 0; j < WINDOW; ++j) {
        const float* wc = wc0 + j * WT_STRIDE;
        float a = 0.0f;
#pragma unroll
        for (int k = 0; k < D; ++k) a += xr[k] * wc[k];
        acc[j] = a * 0.18257418583505536f;   // 1/sqrt(30)
    }
    __syncthreads();   // all row reads done before rows are overwritten

    // ---- assemble output row in LDS (own row only) ----
    float* wr = ws + lane * OT_ROWPAD;
#pragma unroll
    for (int k = 0; k < D; ++k) wr[k] = 0.0f;
#pragma unroll
    for (int j = 0; j < WINDOW; ++j) wr[start + j] = acc[j];
    __syncthreads();   // cross-lane before coalesced store

    // ---- stage-out: 480 contiguous float4, fully coalesced ----
    float4* gout = reinterpret_cast<float4*>(out);
#pragma unroll
    for (int it = 0; it < 8; ++it) {
        const int g = it * 64 + lane;
        if (g < 480 && f4base + g < f4lim) {
            const int pair = g / 15, within = g - pair * 15;
            const int r0 = pair * 2, f0 = within * 4;
            float vv[4];
#pragma unroll
            for (int e = 0; e < 4; ++e) {
                const int ff = f0 + e;
                const int r  = r0 + (ff >= D);
                const int c  = ff - ((ff >= D) ? D : 0);
                vv[e] = ws[r * OT_ROWPAD + c];
            }
            gout[f4base + g] = make_float4(vv[0], vv[1], vv[2], vv[3]);
        }
    }
}

// ===========================================================================
// Fallback (round-2 atomic path) if buffers are unexpectedly small.
// ===========================================================================
#define SAME_INC (1u << 12)
#define DIFF_INC (1u << 22)

__global__ __launch_bounds__(256) void edge_pass_atomic(
    const int* __restrict__ edge_index, const int* __restrict__ atom_types,
    unsigned* __restrict__ agg)
{
    const int t  = blockIdx.x * blockDim.x + threadIdx.x;
    const int e0 = t * 4;
    if (e0 >= N_EDGES) return;
    const int4 s4 = *reinterpret_cast<const int4*>(edge_index + e0);
    const int4 d4 = *reinterpret_cast<const int4*>(edge_index + N_EDGES + e0);
    const int ss[4] = {s4.x, s4.y, s4.z, s4.w};
    const int dd[4] = {d4.x, d4.y, d4.z, d4.w};
#pragma unroll
    for (int k = 0; k < 4; ++k) {
        const int s = ss[k], d = dd[k];
        const unsigned add = 1u + ((atom_types[s] == atom_types[d]) ? SAME_INC : DIFF_INC);
        atomicAdd(agg + s, add);
        atomicAdd(agg + d, add);
    }
}

__global__ __launch_bounds__(256) void out_pass_agg(
    const float* __restrict__ x, const float* __restrict__ Wm,
    const unsigned* __restrict__ agg, const int* __restrict__ atom_types,
    float* __restrict__ out)
{
    __shared__ float sx[64 * D];
    __shared__ float sW[D * D];
    __shared__ int   sstart[64];
    const int tid   = threadIdx.x;
    const long base = (long)blockIdx.x * 64;
    for (int i = tid; i < D * D; i += 256) sW[i] = Wm[i];
    const float* xb = x + base * D;
    for (int i = tid; i < 64 * D; i += 256) sx[i] = xb[i];
    if (tid < 64) {
        const long n = base + tid;
        const unsigned a = agg[n];
        const int cnt = a & 0xFFFu, sc = (a >> 12) & 0x3FFu, dc = a >> 22;
        const int mix  = dc ? 0 : (sc ? atom_types[n] + 1 : 0);
        sstart[tid] = ((cnt > DEG_THRESH ? 3 : 0) + mix) * WINDOW;
    }
    __syncthreads();
    const float scale = 0.18257418583505536f;
    float* ob = out + base * D;
    for (int i = tid; i < 64 * D; i += 256) {
        const int nd = i / D, c = i - nd * D;
        float v = 0.0f;
        if ((unsigned)(c - sstart[nd]) < WINDOW) {
            float acc = 0.0f;
#pragma unroll
            for (int k = 0; k < D; ++k) acc += sx[nd * D + k] * sW[k * D + c];
            v = acc * scale;
        }
        ob[i] = v;
    }
}

// ---------------------------------------------------------------------------
extern "C" void kernel_launch(void* const* d_in, const int* in_sizes, int n_in,
                              void* d_out, int out_size, void* d_ws, size_t ws_size,
                              hipStream_t stream)
{
    const float* x          = (const float*)d_in[0];
    const float* Wm         = (const float*)d_in[1];
    const int*   edge_index = (const int*)d_in[2];
    const int*   atom_types = (const int*)d_in[3];
    float* out = (float*)d_out;

    if (ws_size >= WS_NEEDED && (size_t)out_size * 4 >= OUT_BYTES_NEEDED) {
        char* ws = (char*)d_ws;
        unsigned*       bm       = (unsigned*)(ws + WS_BM_OFF);
        unsigned*       cursors  = (unsigned*)(ws + WS_CUR_OFF);
        unsigned*       partials = (unsigned*)(ws + WS_PART_OFF);
        unsigned short* buckets  = (unsigned short*)d_out;   // scratch, overwritten

        pack_types<<<(N_NODES + 255) / 256, 256, 0, stream>>>(atom_types, bm, cursors);
        bin_edges<<<BIN_BLOCKS, BIN_THREADS, L_TOTAL, stream>>>(edge_index, bm,
                                                                buckets, cursors);
        hist_pass<<<P_PARTS * SLICES, 512, 0, stream>>>(buckets, cursors, partials);
        out_pass<<<(N_NODES + OT_THREADS - 1) / OT_THREADS, OT_THREADS, 0, stream>>>(
            x, Wm, partials, bm, out);
    } else {
        unsigned* agg = (unsigned*)d_ws;
        hipMemsetAsync(agg, 0x00, N_NODES * sizeof(unsigned), stream);
        edge_pass_atomic<<<(N_EDGES / 4) / 256, 256, 0, stream>>>(edge_index, atom_types, agg);
        out_pass_agg<<<N_NODES / 64, 256, 0, stream>>>(x, Wm, agg, atom_types, out);
    }
}